// Round 11
// baseline (126.314 us; speedup 1.0000x reference)
//
#include <hip/hip_runtime.h>
#include <stdint.h>

// Problem constants (fixed-shape problem)
#define NN 10000   // nodes
#define NB 8       // batch
#define NP 12      // periods
#define NT 64      // T
#define NC 32      // C
#define BCAP 64    // bucket capacity per node (Poisson(16): P(>64) ~ 0)
#define FCN 80     // nodes per k_final chunk
#define FCH 125    // chunks (125*80 == NN)
#define XB 3750    // transform blocks (3750*256 = 960000 ushort8 slots)
// x  layout: [b][n][f][p] -> idx = b*960000 + n*96 + k, k = f*12+p
// xh layout: [n][b][k] bf16 -> row of 1536 BYTES per node
// bucket layout: [slot][n]  (transposed: scatter-friendly)
// h1t layout: [n][96]  (r = b*12+p)
// partial layout: [chunk][i*64+t]
// sm layout (floats): [0..11] probs | [16..527] (Mz,Mh) interleaved float2[f*32+c] | [528..591] (cz,ch) float2[c]

typedef float v2f __attribute__((ext_vector_type(2)));

__device__ __forceinline__ v2f up2(unsigned u) {   // 2 bf16 -> v2f
    v2f r;
    r.x = __uint_as_float(u << 16);
    r.y = __uint_as_float(u & 0xffff0000u);
    return r;
}
__device__ __forceinline__ v2f sp(float v) { v2f r; r.x = v; r.y = v; return r; }

// ---------------- zero: deg + count (replaces hipMemsetAsync / fillBufferAligned @ 41us) ----------------
__global__ __launch_bounds__(1024) void k_zero(int* __restrict__ p) {
    p[blockIdx.x * 1024 + threadIdx.x] = 0;
}

// ---------------- prep: transform | edge scatter | smalls ----------------
__global__ __launch_bounds__(256) void k_prep(
    const float* __restrict__ x,
    const int* __restrict__ rowp, const int* __restrict__ colp, const float* __restrict__ ew,
    const float* __restrict__ Wz, const float* __restrict__ bz,
    const float* __restrict__ Wh, const float* __restrict__ bh,
    const float* __restrict__ Lzw, const float* __restrict__ Lzb,
    const float* __restrict__ Lhw, const float* __restrict__ Lhb,
    const float* __restrict__ att,
    float* __restrict__ sm, float* __restrict__ deg, int* __restrict__ count,
    uint2* __restrict__ bucket, unsigned short* __restrict__ xh,
    int E, int EB) {
    const int blk = blockIdx.x, tid = threadIdx.x;
    if (blk < XB) {
        // bf16 transform: slot s = (n*8+b)*12 + q ; write 8 values at xh[s*8]
        const int s = blk * 256 + tid;
        const int n = s / 96, r = s - n * 96;
        const int b = r / 12, q = r - b * 12;
        const float* px = x + (size_t)b * 960000 + n * 96 + q * 8;
        const float4 f0 = *(const float4*)px;
        const float4 f1 = *(const float4*)(px + 4);
        unsigned u0, u1, u2, u3;
        asm("v_cvt_pk_bf16_f32 %0, %1, %2" : "=v"(u0) : "v"(f0.x), "v"(f0.y));
        asm("v_cvt_pk_bf16_f32 %0, %1, %2" : "=v"(u1) : "v"(f0.z), "v"(f0.w));
        asm("v_cvt_pk_bf16_f32 %0, %1, %2" : "=v"(u2) : "v"(f1.x), "v"(f1.y));
        asm("v_cvt_pk_bf16_f32 %0, %1, %2" : "=v"(u3) : "v"(f1.z), "v"(f1.w));
        *(uint4*)(xh + (size_t)s * 8) = make_uint4(u0, u1, u2, u3);
    } else if (blk < XB + EB) {
        const int e = (blk - XB) * 256 + tid;
        if (e < E) {
            const int c = colp[e];
            const float w = ew[e];
            atomicAdd(&deg[c], w);
            const int slot = atomicAdd(&count[c], 1);
            if (slot < BCAP) bucket[slot * NN + c] = make_uint2((unsigned)rowp[e], __float_as_uint(w));
        }
    } else {
        // small matrices (interleaved layout for direct per-lane float2 reads)
        const int t = tid, f = t >> 5, c = t & 31;
        float mz = 0.f, mh = 0.f;
        for (int j = 0; j < NC; ++j) {
            mz += Wz[f * NC + j] * Lzw[j * NC + c];
            mh += Wh[f * NC + j] * Lhw[j * NC + c];
        }
        sm[16 + 2 * t]     = mz;
        sm[16 + 2 * t + 1] = mh;
        if (t < NC) {
            float cz = Lzb[t], ch = Lhb[t];
            for (int j = 0; j < NC; ++j) {
                cz += bz[j] * Lzw[j * NC + t];
                ch += bh[j] * Lhw[j * NC + t];
            }
            sm[528 + 2 * t]     = cz;
            sm[528 + 2 * t + 1] = ch;
        }
        if (t == 0) {
            float m = -1e30f;
            for (int p = 0; p < NP; ++p) m = fmaxf(m, att[p]);
            float e[NP]; float s = 0.f;
            for (int p = 0; p < NP; ++p) { e[p] = __expf(att[p] - m); s += e[p]; }
            for (int p = 0; p < NP; ++p) sm[p] = e[p] / s;
        }
    }
}

#define ACCP(U0, U1, U2, VW)                                          \
    A[0] = __builtin_elementwise_fma(up2(U0.x), VW, A[0]);            \
    A[1] = __builtin_elementwise_fma(up2(U0.y), VW, A[1]);            \
    A[2] = __builtin_elementwise_fma(up2(U1.x), VW, A[2]);            \
    A[3] = __builtin_elementwise_fma(up2(U1.y), VW, A[3]);            \
    A[4] = __builtin_elementwise_fma(up2(U2.x), VW, A[4]);            \
    A[5] = __builtin_elementwise_fma(up2(U2.y), VW, A[5])

// ---------------- main: wave-per-node gather + GRU + lin1 (no barrier, weights from L1/L2) ----------------
template<int PART>
__global__ __launch_bounds__(256) void k_main(
    const unsigned short* __restrict__ xh, const float* __restrict__ deg,
    const int* __restrict__ count, const uint2* __restrict__ bucket,
    const float* __restrict__ sm,
    const float* __restrict__ l1w, const float* __restrict__ l1b,
    float* __restrict__ h1t) {
    __shared__ float sY[4][800];       // per-wave [b*100 + k]
    __shared__ float sHA[4][264];      // per-wave [b*33 + c]
    __shared__ uint2 sE[4][64];        // per-wave edge strip

    const int tid = threadIdx.x;
    const int wv = tid >> 6, l = tid & 63;
    const int n = PART * 5000 + blockIdx.x * 4 + wv;

    // ---- wave-private gather: lane owns 24 bytes (12 bf16) of its node's 1536-byte row ----
    const char* xbase = (const char*)xh;
    const unsigned loff = (unsigned)l * 24u;
    const float dn = rsqrtf(deg[n] + 1.0f);   // dis[n]
    v2f A[6];
    {
        const v2f vsn = sp(dn * dn);   // self-loop norm
        const char* p0 = xbase + ((unsigned)n * 1536u + loff);
        const uint2 u0 = *(const uint2*)p0;
        const uint2 u1 = *(const uint2*)(p0 + 8);
        const uint2 u2 = *(const uint2*)(p0 + 16);
        A[0] = up2(u0.x) * vsn; A[1] = up2(u0.y) * vsn;
        A[2] = up2(u1.x) * vsn; A[3] = up2(u1.y) * vsn;
        A[4] = up2(u2.x) * vsn; A[5] = up2(u2.y) * vsn;
    }
    const int cnt = min(count[n], BCAP);
    uint2* sEw = &sE[wv][0];
    {   // single strip stage (cnt <= 64), zero-weight padding
        uint2 ent = make_uint2(0u, 0u);
        if (l < cnt) {
            const uint2 e = bucket[l * NN + n];   // transposed read
            const float w = __uint_as_float(e.y);
            const float nrm = rsqrtf(deg[e.x] + 1.0f) * w * dn;
            ent = make_uint2(e.x * 1536u, __float_as_uint(nrm));
        }
        sEw[l] = ent;
    }
    const int m4 = (cnt + 3) & ~3;
    for (int q = 0; q < m4; q += 4) {   // 4 edges per iter: 12 loads in flight
        const uint2 e0 = sEw[q + 0], e1 = sEw[q + 1], e2 = sEw[q + 2], e3 = sEw[q + 3];
        const char* pA = xbase + (e0.x + loff);
        const char* pB = xbase + (e1.x + loff);
        const char* pC = xbase + (e2.x + loff);
        const char* pD = xbase + (e3.x + loff);
        const uint2 A0 = *(const uint2*)pA, A1 = *(const uint2*)(pA + 8), A2 = *(const uint2*)(pA + 16);
        const uint2 B0 = *(const uint2*)pB, B1 = *(const uint2*)(pB + 8), B2 = *(const uint2*)(pB + 16);
        const uint2 C0 = *(const uint2*)pC, C1 = *(const uint2*)(pC + 8), C2 = *(const uint2*)(pC + 16);
        const uint2 D0 = *(const uint2*)pD, D1 = *(const uint2*)(pD + 8), D2 = *(const uint2*)(pD + 16);
        const v2f w0 = sp(__uint_as_float(e0.y)), w1 = sp(__uint_as_float(e1.y));
        const v2f w2 = sp(__uint_as_float(e2.y)), w3 = sp(__uint_as_float(e3.y));
        ACCP(A0, A1, A2, w0);
        ACCP(B0, B1, B2, w1);
        ACCP(C0, C1, C2, w2);
        ACCP(D0, D1, D2, w3);
    }
    {   // lane holds (b=l>>3, f=l&7, all 12 p): 3x float4 write
        float* yp = &sY[wv][(l >> 3) * 100 + (l & 7) * 12];
        *(float4*)yp       = make_float4(A[0].x, A[0].y, A[1].x, A[1].y);
        *(float4*)(yp + 4) = make_float4(A[2].x, A[2].y, A[3].x, A[3].y);
        *(float4*)(yp + 8) = make_float4(A[4].x, A[4].y, A[5].x, A[5].y);
    }

    // ---- GRU-collapse (wave-private, packed z/h): lane does 4 tasks; weights direct from global (L1-hit) ----
    const int c = l & 31;
    const float2* __restrict__ smzh = (const float2*)(sm + 16);
    const float2* __restrict__ sczh = (const float2*)(sm + 528);
    v2f m8[8];
    #pragma unroll
    for (int f = 0; f < 8; ++f) { const float2 t2 = smzh[f * 32 + c]; v2f v; v.x = t2.x; v.y = t2.y; m8[f] = v; }
    v2f czh;
    { const float2 t2 = sczh[c]; czh.x = t2.x; czh.y = t2.y; }
    float pr[12];
    #pragma unroll
    for (int p = 0; p < 12; ++p) pr[p] = sm[p];

    #pragma unroll
    for (int t4 = 0; t4 < 4; ++t4) {
        const int b = t4 * 2 + (l >> 5);
        const float* yb = &sY[wv][b * 100];
        v2f zh[12];
        #pragma unroll
        for (int p = 0; p < 12; ++p) zh[p] = czh;
        #pragma unroll
        for (int f = 0; f < 8; ++f) {
            const float4 y0 = *(const float4*)(yb + f * 12);
            const float4 y1 = *(const float4*)(yb + f * 12 + 4);
            const float4 y2 = *(const float4*)(yb + f * 12 + 8);
            const v2f mm = m8[f];
            zh[0]  = __builtin_elementwise_fma(sp(y0.x), mm, zh[0]);
            zh[1]  = __builtin_elementwise_fma(sp(y0.y), mm, zh[1]);
            zh[2]  = __builtin_elementwise_fma(sp(y0.z), mm, zh[2]);
            zh[3]  = __builtin_elementwise_fma(sp(y0.w), mm, zh[3]);
            zh[4]  = __builtin_elementwise_fma(sp(y1.x), mm, zh[4]);
            zh[5]  = __builtin_elementwise_fma(sp(y1.y), mm, zh[5]);
            zh[6]  = __builtin_elementwise_fma(sp(y1.z), mm, zh[6]);
            zh[7]  = __builtin_elementwise_fma(sp(y1.w), mm, zh[7]);
            zh[8]  = __builtin_elementwise_fma(sp(y2.x), mm, zh[8]);
            zh[9]  = __builtin_elementwise_fma(sp(y2.y), mm, zh[9]);
            zh[10] = __builtin_elementwise_fma(sp(y2.z), mm, zh[10]);
            zh[11] = __builtin_elementwise_fma(sp(y2.w), mm, zh[11]);
        }
        float hacc = 0.f;
        #pragma unroll
        for (int p = 0; p < 12; ++p) {
            // (1-sigmoid(sz))*tanh(sh) = u(v-1)/((1+u)(v+1)), u=e^{-sz}, v=e^{2sh}
            const float u = __expf(-zh[p].x);
            const float v = __expf(2.f * zh[p].y);
            const float num = u * (v - 1.f);
            const float den = fmaf(u, v, u) + (v + 1.f);
            hacc = fmaf(pr[p] * num, __builtin_amdgcn_rcpf(den), hacc);
        }
        sHA[wv][b * 33 + c] = fmaxf(hacc, 0.f);
    }

    // ---- lin1 (wave-private): 96 outputs, l1w from L1-resident global ----
    {
        const int r = l;                    // 0..63
        const int bb = r / 12, p = r - bb * 12;
        float s = l1b[p];
        #pragma unroll
        for (int cc = 0; cc < 32; ++cc) s = fmaf(sHA[wv][bb * 33 + cc], l1w[cc * 12 + p], s);
        h1t[n * 96 + r] = s;
    }
    if (l < 32) {
        const int r = l + 64;               // 64..95
        const int bb = r / 12, p = r - bb * 12;
        float s = l1b[p];
        #pragma unroll
        for (int cc = 0; cc < 32; ++cc) s = fmaf(sHA[wv][bb * 33 + cc], l1w[cc * 12 + p], s);
        h1t[n * 96 + r] = s;
    }
}

// ---------------- final stage 1: partial[chunk][i*64+t] = sum_{n in chunk} h1t[n][i] * W2[n][t] ----------------
__global__ __launch_bounds__(256) void k_final(const float* __restrict__ h1t, const float* __restrict__ W2,
                                               float* __restrict__ partial) {
    __shared__ float sh1[96 * FCN];   // 30 KB, [i][nn]
    const int tid = threadIdx.x;
    const int n0 = blockIdx.x * FCN;

    for (int idx = tid; idx < 96 * FCN; idx += 256) {
        const int nn = idx / 96, i = idx - nn * 96;   // consecutive tid -> consecutive i (coalesced h1t row)
        sh1[i * FCN + nn] = h1t[(n0 + nn) * 96 + i];
    }
    __syncthreads();

    const int t = tid & 63, w = tid >> 6;      // 4 waves, each owns 24 i-rows
    const float* sh = &sh1[w * 24 * FCN];
    float acc[24];
    #pragma unroll
    for (int j = 0; j < 24; ++j) acc[j] = 0.f;

    for (int nn = 0; nn < FCN; nn += 4) {
        const float w20 = W2[(n0 + nn + 0) * NT + t];
        const float w21 = W2[(n0 + nn + 1) * NT + t];
        const float w22 = W2[(n0 + nn + 2) * NT + t];
        const float w23 = W2[(n0 + nn + 3) * NT + t];
        #pragma unroll
        for (int j = 0; j < 24; ++j) {
            const float4 hv = *(const float4*)&sh[j * FCN + nn];   // LDS broadcast, 16B-aligned
            acc[j] = fmaf(hv.x, w20, fmaf(hv.y, w21, fmaf(hv.z, w22, fmaf(hv.w, w23, acc[j]))));
        }
    }

    float* pp = partial + blockIdx.x * 6144 + w * 24 * 64 + t;
    #pragma unroll
    for (int j = 0; j < 24; ++j) pp[j * 64] = acc[j];   // coalesced across t
}

// ---------------- final stage 2: out[b][t][p] = l2b[t] + sum_c partial[c][i*64+t] ----------------
__global__ __launch_bounds__(256) void k_red(const float* __restrict__ partial, const float* __restrict__ l2b,
                                             float* __restrict__ out) {
    __shared__ float red[4][64];
    const int i = blockIdx.x;
    const int t = threadIdx.x & 63, g = threadIdx.x >> 6;
    float s = 0.f;
    for (int c = g; c < FCH; c += 4)
        s += partial[c * 6144 + i * 64 + t];     // coalesced across t
    red[g][t] = s;
    __syncthreads();
    if (g == 0) {
        const float v = red[0][t] + red[1][t] + red[2][t] + red[3][t] + l2b[t];
        const int b = i / 12, p = i - b * 12;
        out[b * 768 + t * 12 + p] = v;
    }
}

extern "C" void kernel_launch(void* const* d_in, const int* in_sizes, int n_in,
                              void* d_out, int out_size, void* d_ws, size_t ws_size,
                              hipStream_t stream) {
    const float* x    = (const float*)d_in[0];
    const int*   eidx = (const int*)d_in[1];   // int32 per harness convention
    const float* ew   = (const float*)d_in[2];
    const float* Wz   = (const float*)d_in[3];
    const float* bz   = (const float*)d_in[4];
    // d_in[5], d_in[6]: Wr, br (dead: H0 == 0)
    const float* Wh   = (const float*)d_in[7];
    const float* bh   = (const float*)d_in[8];
    const float* Lzw  = (const float*)d_in[9];
    const float* Lzb  = (const float*)d_in[10];
    // d_in[11], d_in[12]: Lr_w, Lr_b (dead)
    const float* Lhw  = (const float*)d_in[13];
    const float* Lhb  = (const float*)d_in[14];
    const float* att  = (const float*)d_in[15];
    const float* l1w  = (const float*)d_in[16];
    const float* l1b  = (const float*)d_in[17];
    const float* W2   = (const float*)d_in[18];
    const float* l2b  = (const float*)d_in[19];
    float* out = (float*)d_out;
    const int E = in_sizes[2];
    const int EB = (E + 255) / 256;

    // workspace carve-up (all 16B-aligned)
    float* deg    = (float*)d_ws;                       // 10240 f32
    int*   count  = (int*)(deg + 10240);                // 10240 i32
    uint2* bucket = (uint2*)(count + 10240);            // BCAP*NN uint2 = 5.12 MB (transposed)
    float* sm     = (float*)(bucket + NN * BCAP);       // 1024 f32
    float* h1t    = sm + 1024;                          // NN*96 f32
    unsigned short* xh = (unsigned short*)(h1t + NN * 96);   // NN*768 bf16 = 15.36 MB
    float* partial = (float*)(xh + (size_t)NN * 768);   // FCH*6144 f32 = 3.07 MB

    const int* rowp = eidx;        // edge_index[0]
    const int* colp = eidx + E;    // edge_index[1]

    hipLaunchKernelGGL(k_zero, dim3(20), dim3(1024), 0, stream, (int*)d_ws);
    hipLaunchKernelGGL(k_prep, dim3(XB + EB + 1), dim3(256), 0, stream,
                       x, rowp, colp, ew, Wz, bz, Wh, bh, Lzw, Lzb, Lhw, Lhb, att,
                       sm, deg, count, bucket, xh, E, EB);
    k_main<0><<<dim3(1250), dim3(256), 0, stream>>>(xh, deg, count, bucket, sm, l1w, l1b, h1t);
    k_main<1><<<dim3(1250), dim3(256), 0, stream>>>(xh, deg, count, bucket, sm, l1w, l1b, h1t);
    hipLaunchKernelGGL(k_final, dim3(FCH), dim3(256), 0, stream, h1t, W2, partial);
    hipLaunchKernelGGL(k_red, dim3(96), dim3(256), 0, stream, partial, l2b, out);
}

// Round 12
// 112.423 us; speedup vs baseline: 1.1236x; 1.1236x over previous
//
#include <hip/hip_runtime.h>
#include <stdint.h>

// Problem constants (fixed-shape problem)
#define NN 10000   // nodes
#define NNP 10016  // padded nodes (313*32)
#define NB 8       // batch
#define NP 12      // periods
#define NT 64      // T
#define NC 32      // C
#define BCAP 64    // bucket capacity per node (Poisson(16): P(>64) ~ 0)
#define FCN 80     // nodes per k_final chunk
#define FCH 125    // chunks (125*80 == NN)
#define XB 3750    // transform blocks (3750*256 = 960000 ushort8 slots)
// x  layout: [b][n][f][p] -> idx = b*960000 + n*96 + k, k = f*12+p
// xh layout: [b][n][k] bf16, n-stride NNP -> batch slice = 1.92 MB (XCD L2-resident)
// bucket layout: [slot][n]  (transposed: scatter-friendly)
// h1t layout: [n][96]  (r = b*12+p)
// partial layout: [chunk][i*64+t]
// sm layout (floats): [0..11] probs | [16..527] (Mz,Mh) interleaved float2[f*32+c] | [528..591] (cz,ch) float2[c]

typedef float v2f __attribute__((ext_vector_type(2)));

__device__ __forceinline__ v2f up2(unsigned u) {   // 2 bf16 -> v2f
    v2f r;
    r.x = __uint_as_float(u << 16);
    r.y = __uint_as_float(u & 0xffff0000u);
    return r;
}
__device__ __forceinline__ v2f sp(float v) { v2f r; r.x = v; r.y = v; return r; }

// ---------------- zero: deg + count ----------------
__global__ __launch_bounds__(1024) void k_zero(int* __restrict__ p) {
    p[blockIdx.x * 1024 + threadIdx.x] = 0;
}

// ---------------- prep: transform | edge scatter | smalls ----------------
__global__ __launch_bounds__(256) void k_prep(
    const float* __restrict__ x,
    const int* __restrict__ rowp, const int* __restrict__ colp, const float* __restrict__ ew,
    const float* __restrict__ Wz, const float* __restrict__ bz,
    const float* __restrict__ Wh, const float* __restrict__ bh,
    const float* __restrict__ Lzw, const float* __restrict__ Lzb,
    const float* __restrict__ Lhw, const float* __restrict__ Lhb,
    const float* __restrict__ att,
    float* __restrict__ sm, float* __restrict__ deg, int* __restrict__ count,
    uint2* __restrict__ bucket, unsigned short* __restrict__ xh,
    int E, int EB) {
    const int blk = blockIdx.x, tid = threadIdx.x;
    if (blk < XB) {
        // bf16 transform to batch-major: s in [0,960000): b = s/120000, n = rem/12, q = rem%12
        const int s = blk * 256 + tid;
        const int b = s / 120000, rem = s - b * 120000;
        const int n = rem / 12, q = rem - n * 12;
        const float* px = x + (size_t)b * 960000 + n * 96 + q * 8;
        const float4 f0 = *(const float4*)px;
        const float4 f1 = *(const float4*)(px + 4);
        unsigned u0, u1, u2, u3;
        asm("v_cvt_pk_bf16_f32 %0, %1, %2" : "=v"(u0) : "v"(f0.x), "v"(f0.y));
        asm("v_cvt_pk_bf16_f32 %0, %1, %2" : "=v"(u1) : "v"(f0.z), "v"(f0.w));
        asm("v_cvt_pk_bf16_f32 %0, %1, %2" : "=v"(u2) : "v"(f1.x), "v"(f1.y));
        asm("v_cvt_pk_bf16_f32 %0, %1, %2" : "=v"(u3) : "v"(f1.z), "v"(f1.w));
        *(uint4*)(xh + ((size_t)(b * NNP + n) * 12 + q) * 8) = make_uint4(u0, u1, u2, u3);
    } else if (blk < XB + EB) {
        const int e = (blk - XB) * 256 + tid;
        if (e < E) {
            const int c = colp[e];
            const float w = ew[e];
            atomicAdd(&deg[c], w);
            const int slot = atomicAdd(&count[c], 1);
            if (slot < BCAP) bucket[slot * NN + c] = make_uint2((unsigned)rowp[e], __float_as_uint(w));
        }
    } else {
        // small matrices (interleaved layout for direct per-lane float2 reads)
        const int t = tid, f = t >> 5, c = t & 31;
        float mz = 0.f, mh = 0.f;
        for (int j = 0; j < NC; ++j) {
            mz += Wz[f * NC + j] * Lzw[j * NC + c];
            mh += Wh[f * NC + j] * Lhw[j * NC + c];
        }
        sm[16 + 2 * t]     = mz;
        sm[16 + 2 * t + 1] = mh;
        if (t < NC) {
            float cz = Lzb[t], ch = Lhb[t];
            for (int j = 0; j < NC; ++j) {
                cz += bz[j] * Lzw[j * NC + t];
                ch += bh[j] * Lhw[j * NC + t];
            }
            sm[528 + 2 * t]     = cz;
            sm[528 + 2 * t + 1] = ch;
        }
        if (t == 0) {
            float m = -1e30f;
            for (int p = 0; p < NP; ++p) m = fmaxf(m, att[p]);
            float e[NP]; float s = 0.f;
            for (int p = 0; p < NP; ++p) { e[p] = __expf(att[p] - m); s += e[p]; }
            for (int p = 0; p < NP; ++p) sm[p] = e[p] / s;
        }
    }
}

// ---------------- main: batch-pinned XCD-local gather + GRU + lin1 ----------------
// grid = 313*8; b = blockIdx&7 (XCD pin), chunk = blockIdx>>3 (32 nodes).
// Wave owns 8 nodes of batch b; 8-lane group per node (lane owns 12 bf16 = 24 B of 192-B row).
__global__ __launch_bounds__(256) void k_main(
    const unsigned short* __restrict__ xh, const float* __restrict__ deg,
    const int* __restrict__ count, const uint2* __restrict__ bucket,
    const float* __restrict__ sm,
    const float* __restrict__ l1w, const float* __restrict__ l1b,
    float* __restrict__ h1t) {
    __shared__ float sY[4][800];       // per-wave: 8 nodes x stride-100
    __shared__ float sHA[4][264];      // per-wave: 8 nodes x stride-33
    __shared__ uint2 sE[4][64];        // per-wave: 8 groups x 8 staged edges

    const int tid = threadIdx.x;
    const int wv = tid >> 6, l = tid & 63;
    const int b = blockIdx.x & 7;           // == XCD id under round-robin dispatch
    const int chunk = blockIdx.x >> 3;
    const int g = l >> 3, j8 = l & 7;       // group (node slot), lane-in-group
    const int n = chunk * 32 + wv * 8 + g;
    const char* xb = (const char*)(xh + (size_t)b * NNP * 96);

    const int cnt = min(count[n], BCAP);
    const float dn = rsqrtf(deg[n] + 1.0f);
    v2f A[6];
    {   // self-loop
        const v2f vsn = sp(dn * dn);
        const char* p0 = xb + ((unsigned)n * 192u + (unsigned)j8 * 24u);
        const uint2 u0 = *(const uint2*)p0;
        const uint2 u1 = *(const uint2*)(p0 + 8);
        const uint2 u2 = *(const uint2*)(p0 + 16);
        A[0] = up2(u0.x) * vsn; A[1] = up2(u0.y) * vsn;
        A[2] = up2(u1.x) * vsn; A[3] = up2(u1.y) * vsn;
        A[4] = up2(u2.x) * vsn; A[5] = up2(u2.y) * vsn;
    }

    // wave-uniform loop bound: max cnt across the wave's 8 nodes
    int mcnt = cnt;
    #pragma unroll
    for (int off = 1; off < 64; off <<= 1) mcnt = max(mcnt, __shfl_xor(mcnt, off));

    uint2* sEw = &sE[wv][0];
    for (int base = 0; base < mcnt; base += 8) {
        // stage: lane j8 loads edge (base+j8) of its group's node; zero-weight padding
        uint2 ent = make_uint2(0u, 0u);
        const int e = base + j8;
        if (e < cnt) {
            const uint2 be = bucket[e * NN + n];
            const float nrm = rsqrtf(deg[be.x] + 1.0f) * __uint_as_float(be.y) * dn;
            ent = make_uint2(be.x * 192u, __float_as_uint(nrm));
        }
        sEw[l] = ent;   // wave-synchronous
        #pragma unroll
        for (int j = 0; j < 8; ++j) {   // 8 groups consume in parallel -> 8 row-streams in flight
            const uint2 e2 = sEw[g * 8 + j];
            const v2f w = sp(__uint_as_float(e2.y));
            const char* p = xb + (e2.x + (unsigned)j8 * 24u);
            const uint2 u0 = *(const uint2*)p;
            const uint2 u1 = *(const uint2*)(p + 8);
            const uint2 u2 = *(const uint2*)(p + 16);
            A[0] = __builtin_elementwise_fma(up2(u0.x), w, A[0]);
            A[1] = __builtin_elementwise_fma(up2(u0.y), w, A[1]);
            A[2] = __builtin_elementwise_fma(up2(u1.x), w, A[2]);
            A[3] = __builtin_elementwise_fma(up2(u1.y), w, A[3]);
            A[4] = __builtin_elementwise_fma(up2(u2.x), w, A[4]);
            A[5] = __builtin_elementwise_fma(up2(u2.y), w, A[5]);
        }
    }
    {   // lane writes its 12 gathered values: sY[wv][g*100 + j8*12 ..]
        float* yp = &sY[wv][g * 100 + j8 * 12];
        *(float4*)yp       = make_float4(A[0].x, A[0].y, A[1].x, A[1].y);
        *(float4*)(yp + 4) = make_float4(A[2].x, A[2].y, A[3].x, A[3].y);
        *(float4*)(yp + 8) = make_float4(A[4].x, A[4].y, A[5].x, A[5].y);
    }

    // ---- GRU-collapse (wave-private; this batch only): lane does 4 tasks (nd, c) ----
    const int c = l & 31;
    const float2* __restrict__ smzh = (const float2*)(sm + 16);
    const float2* __restrict__ sczh = (const float2*)(sm + 528);
    v2f m8[8];
    #pragma unroll
    for (int f = 0; f < 8; ++f) { const float2 t2 = smzh[f * 32 + c]; v2f v; v.x = t2.x; v.y = t2.y; m8[f] = v; }
    v2f czh;
    { const float2 t2 = sczh[c]; czh.x = t2.x; czh.y = t2.y; }
    float pr[12];
    #pragma unroll
    for (int p = 0; p < 12; ++p) pr[p] = sm[p];

    #pragma unroll
    for (int t4 = 0; t4 < 4; ++t4) {
        const int nd = t4 * 2 + (l >> 5);    // node slot 0..7
        const float* yb = &sY[wv][nd * 100];
        v2f zh[12];
        #pragma unroll
        for (int p = 0; p < 12; ++p) zh[p] = czh;
        #pragma unroll
        for (int f = 0; f < 8; ++f) {
            const float4 y0 = *(const float4*)(yb + f * 12);
            const float4 y1 = *(const float4*)(yb + f * 12 + 4);
            const float4 y2 = *(const float4*)(yb + f * 12 + 8);
            const v2f mm = m8[f];
            zh[0]  = __builtin_elementwise_fma(sp(y0.x), mm, zh[0]);
            zh[1]  = __builtin_elementwise_fma(sp(y0.y), mm, zh[1]);
            zh[2]  = __builtin_elementwise_fma(sp(y0.z), mm, zh[2]);
            zh[3]  = __builtin_elementwise_fma(sp(y0.w), mm, zh[3]);
            zh[4]  = __builtin_elementwise_fma(sp(y1.x), mm, zh[4]);
            zh[5]  = __builtin_elementwise_fma(sp(y1.y), mm, zh[5]);
            zh[6]  = __builtin_elementwise_fma(sp(y1.z), mm, zh[6]);
            zh[7]  = __builtin_elementwise_fma(sp(y1.w), mm, zh[7]);
            zh[8]  = __builtin_elementwise_fma(sp(y2.x), mm, zh[8]);
            zh[9]  = __builtin_elementwise_fma(sp(y2.y), mm, zh[9]);
            zh[10] = __builtin_elementwise_fma(sp(y2.z), mm, zh[10]);
            zh[11] = __builtin_elementwise_fma(sp(y2.w), mm, zh[11]);
        }
        float hacc = 0.f;
        #pragma unroll
        for (int p = 0; p < 12; ++p) {
            // (1-sigmoid(sz))*tanh(sh) = u(v-1)/((1+u)(v+1)), u=e^{-sz}, v=e^{2sh}
            const float u = __expf(-zh[p].x);
            const float v = __expf(2.f * zh[p].y);
            const float num = u * (v - 1.f);
            const float den = fmaf(u, v, u) + (v + 1.f);
            hacc = fmaf(pr[p] * num, __builtin_amdgcn_rcpf(den), hacc);
        }
        sHA[wv][nd * 33 + c] = fmaxf(hacc, 0.f);
    }

    // ---- lin1 (wave-private): 96 tasks (nd 0..7, p 0..11); write h1t[n][b*12+p] ----
    const int n0w = chunk * 32 + wv * 8;
    {
        const int nd = l / 12, p = l - nd * 12;          // tasks 0..63 (nd 0..5)
        if (nd < 8) {
            float s = l1b[p];
            #pragma unroll
            for (int cc = 0; cc < 32; ++cc) s = fmaf(sHA[wv][nd * 33 + cc], l1w[cc * 12 + p], s);
            const int nn = n0w + nd;
            if (nn < NN) h1t[nn * 96 + b * 12 + p] = s;
        }
    }
    if (l < 32) {
        const int task = l + 64;
        const int nd = task / 12, p = task - nd * 12;    // tasks 64..95 (nd 5..7)
        float s = l1b[p];
        #pragma unroll
        for (int cc = 0; cc < 32; ++cc) s = fmaf(sHA[wv][nd * 33 + cc], l1w[cc * 12 + p], s);
        const int nn = n0w + nd;
        if (nn < NN) h1t[nn * 96 + b * 12 + p] = s;
    }
}

// ---------------- final stage 1: partial[chunk][i*64+t] = sum_{n in chunk} h1t[n][i] * W2[n][t] ----------------
__global__ __launch_bounds__(256) void k_final(const float* __restrict__ h1t, const float* __restrict__ W2,
                                               float* __restrict__ partial) {
    __shared__ float sh1[96 * FCN];   // 30 KB, [i][nn]
    const int tid = threadIdx.x;
    const int n0 = blockIdx.x * FCN;

    for (int idx = tid; idx < 96 * FCN; idx += 256) {
        const int nn = idx / 96, i = idx - nn * 96;   // consecutive tid -> consecutive i (coalesced h1t row)
        sh1[i * FCN + nn] = h1t[(n0 + nn) * 96 + i];
    }
    __syncthreads();

    const int t = tid & 63, w = tid >> 6;      // 4 waves, each owns 24 i-rows
    const float* sh = &sh1[w * 24 * FCN];
    float acc[24];
    #pragma unroll
    for (int j = 0; j < 24; ++j) acc[j] = 0.f;

    for (int nn = 0; nn < FCN; nn += 4) {
        const float w20 = W2[(n0 + nn + 0) * NT + t];
        const float w21 = W2[(n0 + nn + 1) * NT + t];
        const float w22 = W2[(n0 + nn + 2) * NT + t];
        const float w23 = W2[(n0 + nn + 3) * NT + t];
        #pragma unroll
        for (int j = 0; j < 24; ++j) {
            const float4 hv = *(const float4*)&sh[j * FCN + nn];   // LDS broadcast, 16B-aligned
            acc[j] = fmaf(hv.x, w20, fmaf(hv.y, w21, fmaf(hv.z, w22, fmaf(hv.w, w23, acc[j]))));
        }
    }

    float* pp = partial + blockIdx.x * 6144 + w * 24 * 64 + t;
    #pragma unroll
    for (int j = 0; j < 24; ++j) pp[j * 64] = acc[j];   // coalesced across t
}

// ---------------- final stage 2: out[b][t][p] = l2b[t] + sum_c partial[c][i*64+t] ----------------
__global__ __launch_bounds__(256) void k_red(const float* __restrict__ partial, const float* __restrict__ l2b,
                                             float* __restrict__ out) {
    __shared__ float red[4][64];
    const int i = blockIdx.x;
    const int t = threadIdx.x & 63, g = threadIdx.x >> 6;
    float s = 0.f;
    for (int c = g; c < FCH; c += 4)
        s += partial[c * 6144 + i * 64 + t];     // coalesced across t
    red[g][t] = s;
    __syncthreads();
    if (g == 0) {
        const float v = red[0][t] + red[1][t] + red[2][t] + red[3][t] + l2b[t];
        const int b = i / 12, p = i - b * 12;
        out[b * 768 + t * 12 + p] = v;
    }
}

extern "C" void kernel_launch(void* const* d_in, const int* in_sizes, int n_in,
                              void* d_out, int out_size, void* d_ws, size_t ws_size,
                              hipStream_t stream) {
    const float* x    = (const float*)d_in[0];
    const int*   eidx = (const int*)d_in[1];   // int32 per harness convention
    const float* ew   = (const float*)d_in[2];
    const float* Wz   = (const float*)d_in[3];
    const float* bz   = (const float*)d_in[4];
    // d_in[5], d_in[6]: Wr, br (dead: H0 == 0)
    const float* Wh   = (const float*)d_in[7];
    const float* bh   = (const float*)d_in[8];
    const float* Lzw  = (const float*)d_in[9];
    const float* Lzb  = (const float*)d_in[10];
    // d_in[11], d_in[12]: Lr_w, Lr_b (dead)
    const float* Lhw  = (const float*)d_in[13];
    const float* Lhb  = (const float*)d_in[14];
    const float* att  = (const float*)d_in[15];
    const float* l1w  = (const float*)d_in[16];
    const float* l1b  = (const float*)d_in[17];
    const float* W2   = (const float*)d_in[18];
    const float* l2b  = (const float*)d_in[19];
    float* out = (float*)d_out;
    const int E = in_sizes[2];
    const int EB = (E + 255) / 256;

    // workspace carve-up (all 16B-aligned)
    float* deg    = (float*)d_ws;                       // 10240 f32
    int*   count  = (int*)(deg + 10240);                // 10240 i32
    uint2* bucket = (uint2*)(count + 10240);            // BCAP*NN uint2 = 5.12 MB (transposed)
    float* sm     = (float*)(bucket + NN * BCAP);       // 1024 f32
    float* h1t    = sm + 1024;                          // NN*96 f32
    unsigned short* xh = (unsigned short*)(h1t + NN * 96);   // NB*NNP*96 bf16 = 15.38 MB
    float* partial = (float*)(xh + (size_t)NB * NNP * 96);   // FCH*6144 f32 = 3.07 MB

    const int* rowp = eidx;        // edge_index[0]
    const int* colp = eidx + E;    // edge_index[1]

    hipLaunchKernelGGL(k_zero, dim3(20), dim3(1024), 0, stream, (int*)d_ws);
    hipLaunchKernelGGL(k_prep, dim3(XB + EB + 1), dim3(256), 0, stream,
                       x, rowp, colp, ew, Wz, bz, Wh, bh, Lzw, Lzb, Lhw, Lhb, att,
                       sm, deg, count, bucket, xh, E, EB);
    hipLaunchKernelGGL(k_main, dim3(313 * 8), dim3(256), 0, stream,
                       xh, deg, count, bucket, sm, l1w, l1b, h1t);
    hipLaunchKernelGGL(k_final, dim3(FCH), dim3(256), 0, stream, h1t, W2, partial);
    hipLaunchKernelGGL(k_red, dim3(96), dim3(256), 0, stream, partial, l2b, out);
}